// Round 2
// baseline (784.430 us; speedup 1.0000x reference)
//
#include <hip/hip_runtime.h>
#include <hip/hip_bf16.h>
#include <stdint.h>

// Qwen3.5 MoE block: router top-2 sparse dispatch + shared expert (SwiGLU), bf16 MFMA.
// B=2,S=1024 -> TOK=2048 tokens. H=2048, I=1408, IS=5632, E=8, K=2.
// Output dtype: FLOAT32 (reference is pure f32 JAX). d_out doubles as the f32 accumulator.
#define TOK   2048
#define HDIM  2048
#define IDIM  1408
#define ISDIM 5632
#define NEXP  8

typedef float  f32x4  __attribute__((ext_vector_type(4)));
typedef short  bf16x8 __attribute__((ext_vector_type(8)));

__device__ __forceinline__ unsigned short f2b(float f) {
  union { float f; uint32_t u; } v; v.f = f;
  return (unsigned short)((v.u + 0x7fffu + ((v.u >> 16) & 1u)) >> 16); // RNE
}

// ---------------- router: logits, top-2 renormalized weights, shared gate ----------------
__global__ __launch_bounds__(256) void router_kernel(
    const float* __restrict__ X, const float* __restrict__ GW,
    const float* __restrict__ SGW, int* __restrict__ cnt,
    int* __restrict__ tok_e, float* __restrict__ tok_w, float* __restrict__ sg)
{
  const int tkn = blockIdx.x, t = threadIdx.x;
  const float* xr = X + (size_t)tkn * HDIM;
  float a[NEXP + 1];
  #pragma unroll
  for (int e = 0; e <= NEXP; ++e) a[e] = 0.f;
  for (int h = t; h < HDIM; h += 256) {
    const float xv = xr[h];
    #pragma unroll
    for (int e = 0; e < NEXP; ++e) a[e] += xv * GW[e * HDIM + h];
    a[NEXP] += xv * SGW[h];
  }
  #pragma unroll
  for (int off = 32; off > 0; off >>= 1) {
    #pragma unroll
    for (int e = 0; e <= NEXP; ++e) a[e] += __shfl_down(a[e], off);
  }
  __shared__ float red[4][NEXP + 1];
  if ((t & 63) == 0) {
    #pragma unroll
    for (int e = 0; e <= NEXP; ++e) red[t >> 6][e] = a[e];
  }
  __syncthreads();
  if (t == 0) {
    float l[NEXP + 1];
    #pragma unroll
    for (int e = 0; e <= NEXP; ++e) l[e] = red[0][e] + red[1][e] + red[2][e] + red[3][e];
    int i1 = 0;
    #pragma unroll
    for (int e = 1; e < NEXP; ++e) if (l[e] > l[i1]) i1 = e;        // first max (stable)
    int i2 = (i1 == 0) ? 1 : 0;
    #pragma unroll
    for (int e = 0; e < NEXP; ++e) if (e != i1 && e != i2 && l[e] > l[i2]) i2 = e;
    // softmax + top2 + renorm == sigmoid of logit difference
    const float w1 = 1.f / (1.f + __expf(l[i2] - l[i1]));
    tok_e[tkn * 2 + 0] = i1; tok_e[tkn * 2 + 1] = i2;
    tok_w[tkn * 2 + 0] = w1; tok_w[tkn * 2 + 1] = 1.f - w1;
    atomicAdd(&cnt[i1], 1); atomicAdd(&cnt[i2], 1);
    sg[tkn] = 1.f / (1.f + __expf(-l[NEXP]));
  }
}

__global__ void scan_kernel(const int* __restrict__ cnt, int* __restrict__ offs) {
  if (threadIdx.x == 0) {
    int r = 0;
    for (int e = 0; e < NEXP; ++e) { offs[e] = r; r += cnt[e]; }
  }
}

__global__ __launch_bounds__(256) void build_kernel(
    const int* __restrict__ tok_e, const float* __restrict__ tok_w,
    const int* __restrict__ offs, int* __restrict__ cur,
    int* __restrict__ list, float* __restrict__ wl)
{
  const int tkn = blockIdx.x * 256 + threadIdx.x;
  if (tkn >= TOK) return;
  #pragma unroll
  for (int k = 0; k < 2; ++k) {
    const int e = tok_e[tkn * 2 + k];
    const int pos = atomicAdd(&cur[e], 1);
    const int slot = offs[e] + pos;
    list[slot] = tkn;
    wl[slot] = tok_w[tkn * 2 + k];
  }
}

// ---------------- fused gate+up SwiGLU GEMM ----------------
// C[slot][n] = silu(X[row]*Wg) * (X[row]*Wu), bf16 out. Tile 128x128, BK=64, 4 waves.
// LDS layout (A and B^T identical): byte(m,k) = m*128 + ((k>>3)^(m&7))*16 + (k&7)*2
template<bool GATHER>
__global__ __launch_bounds__(256) void gateup_kernel(
    const float* __restrict__ X,
    const float* __restrict__ WgA, const float* __restrict__ WuA,
    unsigned short* __restrict__ Cout,
    const int* __restrict__ list, const int* __restrict__ offs,
    const int* __restrict__ cnt, const int N)
{
  __shared__ char smem[49152];
  char* sA  = smem;
  char* sBg = smem + 16384;
  char* sBu = smem + 32768;

  const int t = threadIdx.x;
  const int nt = blockIdx.x;
  int rowbase, mcnt;
  const float *Wg, *Wu;
  if (GATHER) {
    const int e  = blockIdx.y >> 4;
    const int mt = blockIdx.y & 15;
    mcnt = cnt[e] - mt * 128;
    if (mcnt <= 0) return;
    rowbase = offs[e] + mt * 128;
    Wg = WgA + (size_t)e * HDIM * N;
    Wu = WuA + (size_t)e * HDIM * N;
  } else {
    rowbase = blockIdx.y * 128;
    mcnt = 128;
    Wg = WgA; Wu = WuA;
  }
  const int n0 = nt * 128;

  const int w = t >> 6, lane = t & 63;
  const int wr = w >> 1, wc = w & 1;
  const int lcol = lane & 15, lk = lane >> 4;

  f32x4 accg[4][4], accu[4][4];
  #pragma unroll
  for (int i = 0; i < 4; ++i)
    #pragma unroll
    for (int j = 0; j < 4; ++j) { accg[i][j] = {0.f,0.f,0.f,0.f}; accu[i][j] = {0.f,0.f,0.f,0.f}; }

  // A staging map: pass p covers rows m = p*16 + (t>>4), cols k4 = (t&15)*4
  int arow[8];
  #pragma unroll
  for (int p = 0; p < 8; ++p) {
    const int m = p * 16 + (t >> 4);
    arow[p] = GATHER ? list[rowbase + m] : (rowbase + m);  // list zero-padded
  }
  const int ak4 = (t & 15) << 2;
  // B staging map: n = t&127, k-half = t>>7
  const int bn = t & 127, bkh = t >> 7;

  const int KSTEPS = HDIM / 64;
  for (int kt = 0; kt < KSTEPS; ++kt) {
    const int k0 = kt * 64;
    if (kt) __syncthreads();
    // ---- stage A (f32 x -> bf16 swizzled LDS) ----
    #pragma unroll
    for (int p = 0; p < 8; ++p) {
      const int m = p * 16 + (t >> 4);
      const float4 v = *(const float4*)(X + (size_t)arow[p] * HDIM + k0 + ak4);
      ushort4 b; b.x = f2b(v.x); b.y = f2b(v.y); b.z = f2b(v.z); b.w = f2b(v.w);
      *(ushort4*)(sA + m * 128 + ((((ak4 >> 3) ^ (m & 7)) << 4) | ((ak4 & 7) << 1))) = b;
    }
    // ---- stage Bg, Bu: 4 along-K dword loads (coalesced), contiguous 8B LDS write ----
    #pragma unroll
    for (int p = 0; p < 8; ++p) {
      const int k4 = (p << 1) | bkh;                  // 0..15, k = k4*4+j
      const size_t gb = (size_t)(k0 + (k4 << 2)) * N + n0 + bn;
      const int wa = bn * 128 + ((((k4 >> 1) ^ (bn & 7)) << 4) | ((k4 & 1) << 3));
      ushort4 vg, vu;
      vg.x = f2b(Wg[gb]);                 vu.x = f2b(Wu[gb]);
      vg.y = f2b(Wg[gb + (size_t)N]);     vu.y = f2b(Wu[gb + (size_t)N]);
      vg.z = f2b(Wg[gb + 2*(size_t)N]);   vu.z = f2b(Wu[gb + 2*(size_t)N]);
      vg.w = f2b(Wg[gb + 3*(size_t)N]);   vu.w = f2b(Wu[gb + 3*(size_t)N]);
      *(ushort4*)(sBg + wa) = vg;
      *(ushort4*)(sBu + wa) = vu;
    }
    __syncthreads();
    // ---- compute: 2 k-slices x 4x4 fragments, both matrices share A ----
    #pragma unroll
    for (int ks = 0; ks < 2; ++ks) {
      bf16x8 af[4], bg[4], bu[4];
      #pragma unroll
      for (int fm = 0; fm < 4; ++fm) {
        const int m = wr * 64 + fm * 16 + lcol;
        af[fm] = *(const bf16x8*)(sA + m * 128 + (((ks * 4 + lk) ^ (m & 7)) << 4));
      }
      #pragma unroll
      for (int fn = 0; fn < 4; ++fn) {
        const int n = wc * 64 + fn * 16 + lcol;
        const int ra = n * 128 + (((ks * 4 + lk) ^ (n & 7)) << 4);
        bg[fn] = *(const bf16x8*)(sBg + ra);
        bu[fn] = *(const bf16x8*)(sBu + ra);
      }
      #pragma unroll
      for (int fm = 0; fm < 4; ++fm)
        #pragma unroll
        for (int fn = 0; fn < 4; ++fn) {
          accg[fm][fn] = __builtin_amdgcn_mfma_f32_16x16x32_bf16(af[fm], bg[fn], accg[fm][fn], 0, 0, 0);
          accu[fm][fn] = __builtin_amdgcn_mfma_f32_16x16x32_bf16(af[fm], bu[fn], accu[fm][fn], 0, 0, 0);
        }
    }
  }
  // ---- epilogue: h = silu(g)*u -> bf16 ----
  #pragma unroll
  for (int fm = 0; fm < 4; ++fm) {
    #pragma unroll
    for (int fn = 0; fn < 4; ++fn) {
      const int col = n0 + wc * 64 + fn * 16 + lcol;
      #pragma unroll
      for (int r = 0; r < 4; ++r) {
        const int lrow = wr * 64 + fm * 16 + lk * 4 + r;
        if (lrow < mcnt) {
          const float gv = accg[fm][fn][r];
          const float uv = accu[fm][fn][r];
          const float hv = gv * uv / (1.f + __expf(-gv));
          Cout[(size_t)(rowbase + lrow) * N + col] = f2b(hv);
        }
      }
    }
  }
}

// ---------------- down-projection GEMM (f32 output) ----------------
// EXPERT: atomicAdd(out[list[slot]][n], wl[slot]*v). shared: out[row][n] = sg[row]*v.
template<bool EXPERT>
__global__ __launch_bounds__(256) void down_kernel(
    const unsigned short* __restrict__ Abuf,  // bf16 [rows][K]
    const float* __restrict__ Ball,           // f32 [E][K][H] or [K][H]
    float* __restrict__ out,
    const int* __restrict__ list, const float* __restrict__ wl,
    const int* __restrict__ offs, const int* __restrict__ cnt, const int K)
{
  __shared__ char smem[32768];
  char* sA = smem;
  char* sB = smem + 16384;

  const int t = threadIdx.x;
  const int nt = blockIdx.x;
  int rowbase, mcnt;
  const float* Bm;
  if (EXPERT) {
    const int e  = blockIdx.y >> 4;
    const int mt = blockIdx.y & 15;
    mcnt = cnt[e] - mt * 128;
    if (mcnt <= 0) return;
    rowbase = offs[e] + mt * 128;
    Bm = Ball + (size_t)e * K * HDIM;
  } else {
    rowbase = blockIdx.y * 128;
    mcnt = 128;
    Bm = Ball;
  }
  const int n0 = nt * 128;
  const int w = t >> 6, lane = t & 63;
  const int wr = w >> 1, wc = w & 1;
  const int lcol = lane & 15, lk = lane >> 4;

  f32x4 acc[4][4];
  #pragma unroll
  for (int i = 0; i < 4; ++i)
    #pragma unroll
    for (int j = 0; j < 4; ++j) acc[i][j] = {0.f,0.f,0.f,0.f};

  const int bn = t & 127, bkh = t >> 7;

  const int KSTEPS = K / 64;
  for (int kt = 0; kt < KSTEPS; ++kt) {
    const int k0 = kt * 64;
    if (kt) __syncthreads();
    // ---- stage A (bf16, pre-swizzled source -> linear LDS write, conflict-free) ----
    #pragma unroll
    for (int p = 0; p < 4; ++p) {
      const int s = p * 256 + t;
      const int m = s >> 3;
      const int k8 = (s & 7) ^ (m & 7);
      const uint4 v = *(const uint4*)(Abuf + (size_t)(rowbase + m) * K + k0 + (k8 << 3));
      *(uint4*)(sA + s * 16) = v;
    }
    // ---- stage B (f32 w_down -> bf16 transposed swizzled LDS) ----
    #pragma unroll
    for (int p = 0; p < 8; ++p) {
      const int k4 = (p << 1) | bkh;
      const size_t gb = (size_t)(k0 + (k4 << 2)) * HDIM + n0 + bn;
      const int wa = bn * 128 + ((((k4 >> 1) ^ (bn & 7)) << 4) | ((k4 & 1) << 3));
      ushort4 vb;
      vb.x = f2b(Bm[gb]);
      vb.y = f2b(Bm[gb + HDIM]);
      vb.z = f2b(Bm[gb + 2 * HDIM]);
      vb.w = f2b(Bm[gb + 3 * HDIM]);
      *(ushort4*)(sB + wa) = vb;
    }
    __syncthreads();
    #pragma unroll
    for (int ks = 0; ks < 2; ++ks) {
      bf16x8 af[4], bfr[4];
      #pragma unroll
      for (int fm = 0; fm < 4; ++fm) {
        const int m = wr * 64 + fm * 16 + lcol;
        af[fm] = *(const bf16x8*)(sA + m * 128 + (((ks * 4 + lk) ^ (m & 7)) << 4));
      }
      #pragma unroll
      for (int fn = 0; fn < 4; ++fn) {
        const int n = wc * 64 + fn * 16 + lcol;
        bfr[fn] = *(const bf16x8*)(sB + n * 128 + (((ks * 4 + lk) ^ (n & 7)) << 4));
      }
      #pragma unroll
      for (int fm = 0; fm < 4; ++fm)
        #pragma unroll
        for (int fn = 0; fn < 4; ++fn)
          acc[fm][fn] = __builtin_amdgcn_mfma_f32_16x16x32_bf16(af[fm], bfr[fn], acc[fm][fn], 0, 0, 0);
    }
  }
  // ---- epilogue (f32) ----
  #pragma unroll
  for (int fm = 0; fm < 4; ++fm) {
    #pragma unroll
    for (int fn = 0; fn < 4; ++fn) {
      const int col = n0 + wc * 64 + fn * 16 + lcol;
      #pragma unroll
      for (int r = 0; r < 4; ++r) {
        const int lrow = wr * 64 + fm * 16 + lk * 4 + r;
        if (lrow < mcnt) {
          const float v = acc[fm][fn][r];
          if (EXPERT) {
            const int slot = rowbase + lrow;
            atomicAdd(out + (size_t)list[slot] * HDIM + col, wl[slot] * v);
          } else {
            const int row = rowbase + lrow;
            out[(size_t)row * HDIM + col] = wl[row] * v;
          }
        }
      }
    }
  }
}

extern "C" void kernel_launch(void* const* d_in, const int* in_sizes, int n_in,
                              void* d_out, int out_size, void* d_ws, size_t ws_size,
                              hipStream_t stream)
{
  const float* x       = (const float*)d_in[0];
  const float* gate_w  = (const float*)d_in[1];
  const float* w_gate  = (const float*)d_in[2];
  const float* w_up    = (const float*)d_in[3];
  const float* w_down  = (const float*)d_in[4];
  const float* sw_gate = (const float*)d_in[5];
  const float* sw_up   = (const float*)d_in[6];
  const float* sw_down = (const float*)d_in[7];
  const float* sgw     = (const float*)d_in[8];

  float* out = (float*)d_out;   // f32 [TOK][H]; doubles as the accumulator

  // workspace layout (~35 MB)
  char* ws = (char*)d_ws;
  unsigned short* sh_buf = (unsigned short*)ws;                    // 2048*5632*2  = 23,068,672 B
  unsigned short* h_buf  = (unsigned short*)(ws + 23068672);       // 4224*1408*2  = 11,894,784 B
  char* meta = ws + 34963456;
  int*   cnt   = (int*)(meta);
  int*   cur   = (int*)(meta + 256);
  int*   offs  = (int*)(meta + 512);
  int*   list  = (int*)(meta + 768);                 // 4224 ints (zero-padded tail)
  float* wl    = (float*)(meta + 768 + 17152);       // 4224 floats (zero-padded tail)
  int*   tok_e = (int*)(meta + 768 + 2 * 17152);
  float* tok_w = (float*)(meta + 768 + 2 * 17152 + 16384);
  float* sg    = (float*)(meta + 768 + 2 * 17152 + 32768);

  // zero counts/cursors/lists (list/wl padding must be {token 0, weight 0})
  hipMemsetAsync(meta, 0, 768 + 2 * 17152, stream);

  router_kernel<<<TOK, 256, 0, stream>>>(x, gate_w, sgw, cnt, tok_e, tok_w, sg);
  scan_kernel<<<1, 64, 0, stream>>>(cnt, offs);
  build_kernel<<<8, 256, 0, stream>>>(tok_e, tok_w, offs, cur, list, wl);

  // shared expert (writes all of `out` densely -> covers poison), then sparse experts atomicAdd on top
  gateup_kernel<false><<<dim3(ISDIM / 128, TOK / 128), 256, 0, stream>>>(
      x, sw_gate, sw_up, sh_buf, nullptr, nullptr, nullptr, ISDIM);
  down_kernel<false><<<dim3(HDIM / 128, TOK / 128), 256, 0, stream>>>(
      sh_buf, sw_down, out, nullptr, sg, nullptr, nullptr, ISDIM);

  gateup_kernel<true><<<dim3(IDIM / 128, NEXP * 16), 256, 0, stream>>>(
      x, w_gate, w_up, h_buf, list, offs, cnt, IDIM);
  down_kernel<true><<<dim3(HDIM / 128, NEXP * 16), 256, 0, stream>>>(
      h_buf, w_down, out, list, wl, offs, cnt, IDIM);
}

// Round 3
// 645.368 us; speedup vs baseline: 1.2155x; 1.2155x over previous
//
#include <hip/hip_runtime.h>
#include <hip/hip_bf16.h>
#include <stdint.h>

// Qwen3.5 MoE block: router top-2 sparse dispatch + shared expert (SwiGLU), bf16 MFMA.
// B=2,S=1024 -> TOK=2048 tokens. H=2048, I=1408, IS=5632, E=8, K=2. Output f32.
// Round 3: one-shot weight transpose+bf16 conversion so all GEMM staging is wide
// along-K bf16 loads (pre-swizzled source -> linear LDS write, conflict-free).
#define TOK   2048
#define HDIM  2048
#define IDIM  1408
#define ISDIM 5632
#define NEXP  8

typedef float  f32x4  __attribute__((ext_vector_type(4)));
typedef short  bf16x8 __attribute__((ext_vector_type(8)));

__device__ __forceinline__ unsigned short f2b(float f) {
  union { float f; uint32_t u; } v; v.f = f;
  return (unsigned short)((v.u + 0x7fffu + ((v.u >> 16) & 1u)) >> 16); // RNE
}

// ---------------- router ----------------
__global__ __launch_bounds__(256) void router_kernel(
    const float* __restrict__ X, const float* __restrict__ GW,
    const float* __restrict__ SGW, int* __restrict__ cnt,
    int* __restrict__ tok_e, float* __restrict__ tok_w, float* __restrict__ sg)
{
  const int tkn = blockIdx.x, t = threadIdx.x;
  const float* xr = X + (size_t)tkn * HDIM;
  float a[NEXP + 1];
  #pragma unroll
  for (int e = 0; e <= NEXP; ++e) a[e] = 0.f;
  for (int h = t; h < HDIM; h += 256) {
    const float xv = xr[h];
    #pragma unroll
    for (int e = 0; e < NEXP; ++e) a[e] += xv * GW[e * HDIM + h];
    a[NEXP] += xv * SGW[h];
  }
  #pragma unroll
  for (int off = 32; off > 0; off >>= 1) {
    #pragma unroll
    for (int e = 0; e <= NEXP; ++e) a[e] += __shfl_down(a[e], off);
  }
  __shared__ float red[4][NEXP + 1];
  if ((t & 63) == 0) {
    #pragma unroll
    for (int e = 0; e <= NEXP; ++e) red[t >> 6][e] = a[e];
  }
  __syncthreads();
  if (t == 0) {
    float l[NEXP + 1];
    #pragma unroll
    for (int e = 0; e <= NEXP; ++e) l[e] = red[0][e] + red[1][e] + red[2][e] + red[3][e];
    int i1 = 0;
    #pragma unroll
    for (int e = 1; e < NEXP; ++e) if (l[e] > l[i1]) i1 = e;
    int i2 = (i1 == 0) ? 1 : 0;
    #pragma unroll
    for (int e = 0; e < NEXP; ++e) if (e != i1 && e != i2 && l[e] > l[i2]) i2 = e;
    const float w1 = 1.f / (1.f + __expf(l[i2] - l[i1]));   // softmax+top2+renorm == sigmoid(diff)
    tok_e[tkn * 2 + 0] = i1; tok_e[tkn * 2 + 1] = i2;
    tok_w[tkn * 2 + 0] = w1; tok_w[tkn * 2 + 1] = 1.f - w1;
    atomicAdd(&cnt[i1], 1); atomicAdd(&cnt[i2], 1);
    sg[tkn] = 1.f / (1.f + __expf(-l[NEXP]));
  }
}

__global__ void scan_kernel(const int* __restrict__ cnt, int* __restrict__ offs) {
  if (threadIdx.x == 0) {
    int r = 0;
    for (int e = 0; e < NEXP; ++e) { offs[e] = r; r += cnt[e]; }
  }
}

__global__ __launch_bounds__(256) void build_kernel(
    const int* __restrict__ tok_e, const float* __restrict__ tok_w,
    const int* __restrict__ offs, int* __restrict__ cur,
    int* __restrict__ list, float* __restrict__ wl)
{
  const int tkn = blockIdx.x * 256 + threadIdx.x;
  if (tkn >= TOK) return;
  #pragma unroll
  for (int k = 0; k < 2; ++k) {
    const int e = tok_e[tkn * 2 + k];
    const int pos = atomicAdd(&cur[e], 1);
    const int slot = offs[e] + pos;
    list[slot] = tkn;
    wl[slot] = tok_w[tkn * 2 + k];
  }
}

// ---------------- preprocessing ----------------
// f32 -> bf16 elementwise (X)
__global__ __launch_bounds__(256) void cvt_kernel(
    const float* __restrict__ src, unsigned short* __restrict__ dst, int n4)
{
  const int i = blockIdx.x * 512 + threadIdx.x;
  #pragma unroll
  for (int p = 0; p < 2; ++p) {
    const int j = i + p * 256;
    if (j < n4) {
      const float4 v = ((const float4*)src)[j];
      ushort4 b; b.x = f2b(v.x); b.y = f2b(v.y); b.z = f2b(v.z); b.w = f2b(v.w);
      ((ushort4*)dst)[j] = b;
    }
  }
}

// f32 [R][C] -> bf16 [C][R], per-z matrix. grid (C/64, R/64, nmat)
__global__ __launch_bounds__(256) void transpose_cvt_kernel(
    const float* __restrict__ src, unsigned short* __restrict__ dst,
    const int R, const int C)
{
  __shared__ unsigned short tile[64][72];   // [col][row], stride 72 for aligned b128 reads
  const size_t mat = (size_t)blockIdx.z * R * C;
  const int c0 = blockIdx.x * 64, r0 = blockIdx.y * 64;
  const int t = threadIdx.x;
  const int rr = t >> 4, cc = (t & 15) * 4;
  #pragma unroll
  for (int p = 0; p < 4; ++p) {
    const int r = rr + p * 16;
    const float4 v = *(const float4*)(src + mat + (size_t)(r0 + r) * C + c0 + cc);
    tile[cc + 0][r] = f2b(v.x);
    tile[cc + 1][r] = f2b(v.y);
    tile[cc + 2][r] = f2b(v.z);
    tile[cc + 3][r] = f2b(v.w);
  }
  __syncthreads();
  #pragma unroll
  for (int p = 0; p < 2; ++p) {
    const int id = p * 256 + t;
    const int c = id >> 3, q = id & 7;
    const uint4 v = *(const uint4*)&tile[c][q * 8];
    *(uint4*)(dst + mat + (size_t)(c0 + c) * R + r0 + q * 8) = v;
  }
}

// ---------------- bf16 GEMM kernels (pre-transposed B: [N][K]) ----------------
// LDS granule layout (both operands): tile row m (128 rows), granule g (8 x 16B):
//   LDS[m*128 + g*16] holds source k-granule k8 = g ^ (m&7)   (XOR swizzle)
// Fragment read: bf16x8 at m*128 + ((k8 ^ (m&7)) << 4) -- conflict-reduced ds_read_b128.

template<bool GATHER>
__global__ __launch_bounds__(256) void gateup_bf_kernel(
    const unsigned short* __restrict__ Xb,   // bf16 [TOK][HDIM]
    const unsigned short* __restrict__ WgT,  // bf16 [(E)][N][HDIM]
    const unsigned short* __restrict__ WuT,
    unsigned short* __restrict__ Cout,       // bf16 [rows][N]
    const int* __restrict__ list, const int* __restrict__ offs,
    const int* __restrict__ cnt, const int N)
{
  __shared__ char smem[49152];
  char* sA  = smem;
  char* sBg = smem + 16384;
  char* sBu = smem + 32768;

  const int t = threadIdx.x;
  const int nt = blockIdx.x;
  int rowbase, mcnt;
  const unsigned short *Wg, *Wu;
  if (GATHER) {
    const int e  = blockIdx.y >> 4;
    const int mt = blockIdx.y & 15;
    mcnt = cnt[e] - mt * 128;
    if (mcnt <= 0) return;
    rowbase = offs[e] + mt * 128;
    Wg = WgT + (size_t)e * N * HDIM;
    Wu = WuT + (size_t)e * N * HDIM;
  } else {
    rowbase = blockIdx.y * 128;
    mcnt = 128;
    Wg = WgT; Wu = WuT;
  }
  const int n0 = nt * 128;

  const int w = t >> 6, lane = t & 63;
  const int wr = w >> 1, wc = w & 1;
  const int lcol = lane & 15, lk = lane >> 4;

  f32x4 accg[4][4], accu[4][4];
  #pragma unroll
  for (int i = 0; i < 4; ++i)
    #pragma unroll
    for (int j = 0; j < 4; ++j) { accg[i][j] = {0.f,0.f,0.f,0.f}; accu[i][j] = {0.f,0.f,0.f,0.f}; }

  // staging map: granule s = p*256 + t; m = s>>3; k8 = (s&7)^(m&7)
  int arow[4], bm[4], koff[4];
  #pragma unroll
  for (int p = 0; p < 4; ++p) {
    const int s = p * 256 + t;
    const int m = s >> 3;
    bm[p] = m;
    koff[p] = ((s & 7) ^ (m & 7)) << 3;
    arow[p] = GATHER ? list[rowbase + m] : (rowbase + m);   // list zero-padded
  }

  const int KSTEPS = HDIM / 64;
  for (int kt = 0; kt < KSTEPS; ++kt) {
    const int k0 = kt * 64;
    if (kt) __syncthreads();
    #pragma unroll
    for (int p = 0; p < 4; ++p) {
      const int s16 = (p * 256 + t) * 16;
      *(uint4*)(sA  + s16) = *(const uint4*)(Xb + (size_t)arow[p] * HDIM + k0 + koff[p]);
      *(uint4*)(sBg + s16) = *(const uint4*)(Wg + (size_t)(n0 + bm[p]) * HDIM + k0 + koff[p]);
      *(uint4*)(sBu + s16) = *(const uint4*)(Wu + (size_t)(n0 + bm[p]) * HDIM + k0 + koff[p]);
    }
    __syncthreads();
    #pragma unroll
    for (int ks = 0; ks < 2; ++ks) {
      bf16x8 af[4], bg[4], bu[4];
      #pragma unroll
      for (int fm = 0; fm < 4; ++fm) {
        const int m = wr * 64 + fm * 16 + lcol;
        af[fm] = *(const bf16x8*)(sA + m * 128 + (((ks * 4 + lk) ^ (m & 7)) << 4));
      }
      #pragma unroll
      for (int fn = 0; fn < 4; ++fn) {
        const int n = wc * 64 + fn * 16 + lcol;
        const int ra = n * 128 + (((ks * 4 + lk) ^ (n & 7)) << 4);
        bg[fn] = *(const bf16x8*)(sBg + ra);
        bu[fn] = *(const bf16x8*)(sBu + ra);
      }
      #pragma unroll
      for (int fm = 0; fm < 4; ++fm)
        #pragma unroll
        for (int fn = 0; fn < 4; ++fn) {
          accg[fm][fn] = __builtin_amdgcn_mfma_f32_16x16x32_bf16(af[fm], bg[fn], accg[fm][fn], 0, 0, 0);
          accu[fm][fn] = __builtin_amdgcn_mfma_f32_16x16x32_bf16(af[fm], bu[fn], accu[fm][fn], 0, 0, 0);
        }
    }
  }
  #pragma unroll
  for (int fm = 0; fm < 4; ++fm) {
    #pragma unroll
    for (int fn = 0; fn < 4; ++fn) {
      const int col = n0 + wc * 64 + fn * 16 + lcol;
      #pragma unroll
      for (int r = 0; r < 4; ++r) {
        const int lrow = wr * 64 + fm * 16 + lk * 4 + r;
        if (lrow < mcnt) {
          const float gv = accg[fm][fn][r];
          const float uv = accu[fm][fn][r];
          const float hv = gv * uv / (1.f + __expf(-gv));
          Cout[(size_t)(rowbase + lrow) * N + col] = f2b(hv);
        }
      }
    }
  }
}

template<bool EXPERT>
__global__ __launch_bounds__(256) void down_bf_kernel(
    const unsigned short* __restrict__ Abuf,  // bf16 [rows][K]
    const unsigned short* __restrict__ BT,    // bf16 [(E)][HDIM][K]
    float* __restrict__ out,
    const int* __restrict__ list, const float* __restrict__ wl,
    const int* __restrict__ offs, const int* __restrict__ cnt, const int K)
{
  __shared__ char smem[32768];
  char* sA = smem;
  char* sB = smem + 16384;

  const int t = threadIdx.x;
  const int nt = blockIdx.x;
  int rowbase, mcnt;
  const unsigned short* Bm;
  if (EXPERT) {
    const int e  = blockIdx.y >> 4;
    const int mt = blockIdx.y & 15;
    mcnt = cnt[e] - mt * 128;
    if (mcnt <= 0) return;
    rowbase = offs[e] + mt * 128;
    Bm = BT + (size_t)e * HDIM * K;
  } else {
    rowbase = blockIdx.y * 128;
    mcnt = 128;
    Bm = BT;
  }
  const int n0 = nt * 128;
  const int w = t >> 6, lane = t & 63;
  const int wr = w >> 1, wc = w & 1;
  const int lcol = lane & 15, lk = lane >> 4;

  f32x4 acc[4][4];
  #pragma unroll
  for (int i = 0; i < 4; ++i)
    #pragma unroll
    for (int j = 0; j < 4; ++j) acc[i][j] = {0.f,0.f,0.f,0.f};

  int bm[4], koff[4];
  #pragma unroll
  for (int p = 0; p < 4; ++p) {
    const int s = p * 256 + t;
    const int m = s >> 3;
    bm[p] = m;
    koff[p] = ((s & 7) ^ (m & 7)) << 3;
  }

  const int KSTEPS = K / 64;
  for (int kt = 0; kt < KSTEPS; ++kt) {
    const int k0 = kt * 64;
    if (kt) __syncthreads();
    #pragma unroll
    for (int p = 0; p < 4; ++p) {
      const int s16 = (p * 256 + t) * 16;
      *(uint4*)(sA + s16) = *(const uint4*)(Abuf + (size_t)(rowbase + bm[p]) * K + k0 + koff[p]);
      *(uint4*)(sB + s16) = *(const uint4*)(Bm + (size_t)(n0 + bm[p]) * K + k0 + koff[p]);
    }
    __syncthreads();
    #pragma unroll
    for (int ks = 0; ks < 2; ++ks) {
      bf16x8 af[4], bfr[4];
      #pragma unroll
      for (int fm = 0; fm < 4; ++fm) {
        const int m = wr * 64 + fm * 16 + lcol;
        af[fm] = *(const bf16x8*)(sA + m * 128 + (((ks * 4 + lk) ^ (m & 7)) << 4));
      }
      #pragma unroll
      for (int fn = 0; fn < 4; ++fn) {
        const int n = wc * 64 + fn * 16 + lcol;
        bfr[fn] = *(const bf16x8*)(sB + n * 128 + (((ks * 4 + lk) ^ (n & 7)) << 4));
      }
      #pragma unroll
      for (int fm = 0; fm < 4; ++fm)
        #pragma unroll
        for (int fn = 0; fn < 4; ++fn)
          acc[fm][fn] = __builtin_amdgcn_mfma_f32_16x16x32_bf16(af[fm], bfr[fn], acc[fm][fn], 0, 0, 0);
    }
  }
  #pragma unroll
  for (int fm = 0; fm < 4; ++fm) {
    #pragma unroll
    for (int fn = 0; fn < 4; ++fn) {
      const int col = n0 + wc * 64 + fn * 16 + lcol;
      #pragma unroll
      for (int r = 0; r < 4; ++r) {
        const int lrow = wr * 64 + fm * 16 + lk * 4 + r;
        if (lrow < mcnt) {
          const float v = acc[fm][fn][r];
          if (EXPERT) {
            const int slot = rowbase + lrow;
            atomicAdd(out + (size_t)list[slot] * HDIM + col, wl[slot] * v);
          } else {
            const int row = rowbase + lrow;
            out[(size_t)row * HDIM + col] = wl[row] * v;
          }
        }
      }
    }
  }
}

// ================= legacy f32-weight path (fallback if ws too small) =================
template<bool GATHER>
__global__ __launch_bounds__(256) void gateup_kernel(
    const float* __restrict__ X,
    const float* __restrict__ WgA, const float* __restrict__ WuA,
    unsigned short* __restrict__ Cout,
    const int* __restrict__ list, const int* __restrict__ offs,
    const int* __restrict__ cnt, const int N)
{
  __shared__ char smem[49152];
  char* sA  = smem;
  char* sBg = smem + 16384;
  char* sBu = smem + 32768;
  const int t = threadIdx.x;
  const int nt = blockIdx.x;
  int rowbase, mcnt;
  const float *Wg, *Wu;
  if (GATHER) {
    const int e  = blockIdx.y >> 4;
    const int mt = blockIdx.y & 15;
    mcnt = cnt[e] - mt * 128;
    if (mcnt <= 0) return;
    rowbase = offs[e] + mt * 128;
    Wg = WgA + (size_t)e * HDIM * N;
    Wu = WuA + (size_t)e * HDIM * N;
  } else {
    rowbase = blockIdx.y * 128;
    mcnt = 128;
    Wg = WgA; Wu = WuA;
  }
  const int n0 = nt * 128;
  const int w = t >> 6, lane = t & 63;
  const int wr = w >> 1, wc = w & 1;
  const int lcol = lane & 15, lk = lane >> 4;
  f32x4 accg[4][4], accu[4][4];
  #pragma unroll
  for (int i = 0; i < 4; ++i)
    #pragma unroll
    for (int j = 0; j < 4; ++j) { accg[i][j] = {0.f,0.f,0.f,0.f}; accu[i][j] = {0.f,0.f,0.f,0.f}; }
  int arow[8];
  #pragma unroll
  for (int p = 0; p < 8; ++p) {
    const int m = p * 16 + (t >> 4);
    arow[p] = GATHER ? list[rowbase + m] : (rowbase + m);
  }
  const int ak4 = (t & 15) << 2;
  const int bn = t & 127, bkh = t >> 7;
  const int KSTEPS = HDIM / 64;
  for (int kt = 0; kt < KSTEPS; ++kt) {
    const int k0 = kt * 64;
    if (kt) __syncthreads();
    #pragma unroll
    for (int p = 0; p < 8; ++p) {
      const int m = p * 16 + (t >> 4);
      const float4 v = *(const float4*)(X + (size_t)arow[p] * HDIM + k0 + ak4);
      ushort4 b; b.x = f2b(v.x); b.y = f2b(v.y); b.z = f2b(v.z); b.w = f2b(v.w);
      *(ushort4*)(sA + m * 128 + ((((ak4 >> 3) ^ (m & 7)) << 4) | ((ak4 & 7) << 1))) = b;
    }
    #pragma unroll
    for (int p = 0; p < 8; ++p) {
      const int k4 = (p << 1) | bkh;
      const size_t gb = (size_t)(k0 + (k4 << 2)) * N + n0 + bn;
      const int wa = bn * 128 + ((((k4 >> 1) ^ (bn & 7)) << 4) | ((k4 & 1) << 3));
      ushort4 vg, vu;
      vg.x = f2b(Wg[gb]);                 vu.x = f2b(Wu[gb]);
      vg.y = f2b(Wg[gb + (size_t)N]);     vu.y = f2b(Wu[gb + (size_t)N]);
      vg.z = f2b(Wg[gb + 2*(size_t)N]);   vu.z = f2b(Wu[gb + 2*(size_t)N]);
      vg.w = f2b(Wg[gb + 3*(size_t)N]);   vu.w = f2b(Wu[gb + 3*(size_t)N]);
      *(ushort4*)(sBg + wa) = vg;
      *(ushort4*)(sBu + wa) = vu;
    }
    __syncthreads();
    #pragma unroll
    for (int ks = 0; ks < 2; ++ks) {
      bf16x8 af[4], bg[4], bu[4];
      #pragma unroll
      for (int fm = 0; fm < 4; ++fm) {
        const int m = wr * 64 + fm * 16 + lcol;
        af[fm] = *(const bf16x8*)(sA + m * 128 + (((ks * 4 + lk) ^ (m & 7)) << 4));
      }
      #pragma unroll
      for (int fn = 0; fn < 4; ++fn) {
        const int n = wc * 64 + fn * 16 + lcol;
        const int ra = n * 128 + (((ks * 4 + lk) ^ (n & 7)) << 4);
        bg[fn] = *(const bf16x8*)(sBg + ra);
        bu[fn] = *(const bf16x8*)(sBu + ra);
      }
      #pragma unroll
      for (int fm = 0; fm < 4; ++fm)
        #pragma unroll
        for (int fn = 0; fn < 4; ++fn) {
          accg[fm][fn] = __builtin_amdgcn_mfma_f32_16x16x32_bf16(af[fm], bg[fn], accg[fm][fn], 0, 0, 0);
          accu[fm][fn] = __builtin_amdgcn_mfma_f32_16x16x32_bf16(af[fm], bu[fn], accu[fm][fn], 0, 0, 0);
        }
    }
  }
  #pragma unroll
  for (int fm = 0; fm < 4; ++fm) {
    #pragma unroll
    for (int fn = 0; fn < 4; ++fn) {
      const int col = n0 + wc * 64 + fn * 16 + lcol;
      #pragma unroll
      for (int r = 0; r < 4; ++r) {
        const int lrow = wr * 64 + fm * 16 + lk * 4 + r;
        if (lrow < mcnt) {
          const float gv = accg[fm][fn][r];
          const float uv = accu[fm][fn][r];
          Cout[(size_t)(rowbase + lrow) * N + col] = f2b(gv * uv / (1.f + __expf(-gv)));
        }
      }
    }
  }
}

template<bool EXPERT>
__global__ __launch_bounds__(256) void down_kernel(
    const unsigned short* __restrict__ Abuf,
    const float* __restrict__ Ball,
    float* __restrict__ out,
    const int* __restrict__ list, const float* __restrict__ wl,
    const int* __restrict__ offs, const int* __restrict__ cnt, const int K)
{
  __shared__ char smem[32768];
  char* sA = smem;
  char* sB = smem + 16384;
  const int t = threadIdx.x;
  const int nt = blockIdx.x;
  int rowbase, mcnt;
  const float* Bm;
  if (EXPERT) {
    const int e  = blockIdx.y >> 4;
    const int mt = blockIdx.y & 15;
    mcnt = cnt[e] - mt * 128;
    if (mcnt <= 0) return;
    rowbase = offs[e] + mt * 128;
    Bm = Ball + (size_t)e * K * HDIM;
  } else {
    rowbase = blockIdx.y * 128;
    mcnt = 128;
    Bm = Ball;
  }
  const int n0 = nt * 128;
  const int w = t >> 6, lane = t & 63;
  const int wr = w >> 1, wc = w & 1;
  const int lcol = lane & 15, lk = lane >> 4;
  f32x4 acc[4][4];
  #pragma unroll
  for (int i = 0; i < 4; ++i)
    #pragma unroll
    for (int j = 0; j < 4; ++j) acc[i][j] = {0.f,0.f,0.f,0.f};
  const int bn = t & 127, bkh = t >> 7;
  const int KSTEPS = K / 64;
  for (int kt = 0; kt < KSTEPS; ++kt) {
    const int k0 = kt * 64;
    if (kt) __syncthreads();
    #pragma unroll
    for (int p = 0; p < 4; ++p) {
      const int s = p * 256 + t;
      const int m = s >> 3;
      const int k8 = (s & 7) ^ (m & 7);
      const uint4 v = *(const uint4*)(Abuf + (size_t)(rowbase + m) * K + k0 + (k8 << 3));
      *(uint4*)(sA + s * 16) = v;
    }
    #pragma unroll
    for (int p = 0; p < 8; ++p) {
      const int k4 = (p << 1) | bkh;
      const size_t gb = (size_t)(k0 + (k4 << 2)) * HDIM + n0 + bn;
      const int wa = bn * 128 + ((((k4 >> 1) ^ (bn & 7)) << 4) | ((k4 & 1) << 3));
      ushort4 vb;
      vb.x = f2b(Bm[gb]);
      vb.y = f2b(Bm[gb + HDIM]);
      vb.z = f2b(Bm[gb + 2 * HDIM]);
      vb.w = f2b(Bm[gb + 3 * HDIM]);
      *(ushort4*)(sB + wa) = vb;
    }
    __syncthreads();
    #pragma unroll
    for (int ks = 0; ks < 2; ++ks) {
      bf16x8 af[4], bfr[4];
      #pragma unroll
      for (int fm = 0; fm < 4; ++fm) {
        const int m = wr * 64 + fm * 16 + lcol;
        af[fm] = *(const bf16x8*)(sA + m * 128 + (((ks * 4 + lk) ^ (m & 7)) << 4));
      }
      #pragma unroll
      for (int fn = 0; fn < 4; ++fn) {
        const int n = wc * 64 + fn * 16 + lcol;
        bfr[fn] = *(const bf16x8*)(sB + n * 128 + (((ks * 4 + lk) ^ (n & 7)) << 4));
      }
      #pragma unroll
      for (int fm = 0; fm < 4; ++fm)
        #pragma unroll
        for (int fn = 0; fn < 4; ++fn)
          acc[fm][fn] = __builtin_amdgcn_mfma_f32_16x16x32_bf16(af[fm], bfr[fn], acc[fm][fn], 0, 0, 0);
    }
  }
  #pragma unroll
  for (int fm = 0; fm < 4; ++fm) {
    #pragma unroll
    for (int fn = 0; fn < 4; ++fn) {
      const int col = n0 + wc * 64 + fn * 16 + lcol;
      #pragma unroll
      for (int r = 0; r < 4; ++r) {
        const int lrow = wr * 64 + fm * 16 + lk * 4 + r;
        if (lrow < mcnt) {
          const float v = acc[fm][fn][r];
          if (EXPERT) {
            const int slot = rowbase + lrow;
            atomicAdd(out + (size_t)list[slot] * HDIM + col, wl[slot] * v);
          } else {
            const int row = rowbase + lrow;
            out[(size_t)row * HDIM + col] = wl[row] * v;
          }
        }
      }
    }
  }
}

extern "C" void kernel_launch(void* const* d_in, const int* in_sizes, int n_in,
                              void* d_out, int out_size, void* d_ws, size_t ws_size,
                              hipStream_t stream)
{
  const float* x       = (const float*)d_in[0];
  const float* gate_w  = (const float*)d_in[1];
  const float* w_gate  = (const float*)d_in[2];
  const float* w_up    = (const float*)d_in[3];
  const float* w_down  = (const float*)d_in[4];
  const float* sw_gate = (const float*)d_in[5];
  const float* sw_up   = (const float*)d_in[6];
  const float* sw_down = (const float*)d_in[7];
  const float* sgw     = (const float*)d_in[8];

  float* out = (float*)d_out;   // f32 [TOK][H]; doubles as the accumulator
  char* ws = (char*)d_ws;

  const size_t NEED = 136000000;   // new-path peak footprint (~135.7 MB)

  if (ws_size >= NEED) {
    // ---- new path: bf16 pre-transposed weights, time-shared buffers ----
    unsigned short* Xb   = (unsigned short*)ws;                     //  8,388,608
    unsigned short* R1a  = (unsigned short*)(ws + 8388608);         // 46,137,344
    unsigned short* R1b  = (unsigned short*)(ws + 54525952);        // 46,137,344
    unsigned short* shb  = (unsigned short*)(ws + 100663296);       // 23,068,672
    unsigned short* hb   = (unsigned short*)(ws + 123731968);       // 11,894,784
    char* meta = ws + 135626752;
    int*   cnt   = (int*)(meta);
    int*   cur   = (int*)(meta + 256);
    int*   offs  = (int*)(meta + 512);
    int*   list  = (int*)(meta + 768);
    float* wl    = (float*)(meta + 768 + 17152);
    int*   tok_e = (int*)(meta + 768 + 2 * 17152);
    float* tok_w = (float*)(meta + 768 + 2 * 17152 + 16384);
    float* sg    = (float*)(meta + 768 + 2 * 17152 + 32768);

    hipMemsetAsync(meta, 0, 768 + 2 * 17152, stream);

    cvt_kernel<<<TOK * HDIM / 4 / 512, 256, 0, stream>>>(x, Xb, TOK * HDIM / 4);
    router_kernel<<<TOK, 256, 0, stream>>>(x, gate_w, sgw, cnt, tok_e, tok_w, sg);
    scan_kernel<<<1, 64, 0, stream>>>(cnt, offs);
    build_kernel<<<8, 256, 0, stream>>>(tok_e, tok_w, offs, cur, list, wl);

    // shared gateup
    transpose_cvt_kernel<<<dim3(ISDIM / 64, HDIM / 64, 1), 256, 0, stream>>>(sw_gate, R1a, HDIM, ISDIM);
    transpose_cvt_kernel<<<dim3(ISDIM / 64, HDIM / 64, 1), 256, 0, stream>>>(sw_up,   R1b, HDIM, ISDIM);
    gateup_bf_kernel<false><<<dim3(ISDIM / 128, TOK / 128), 256, 0, stream>>>(
        Xb, R1a, R1b, shb, nullptr, nullptr, nullptr, ISDIM);
    // shared down
    transpose_cvt_kernel<<<dim3(HDIM / 64, ISDIM / 64, 1), 256, 0, stream>>>(sw_down, R1a, ISDIM, HDIM);
    down_bf_kernel<false><<<dim3(HDIM / 128, TOK / 128), 256, 0, stream>>>(
        shb, R1a, out, nullptr, sg, nullptr, nullptr, ISDIM);
    // expert gateup
    transpose_cvt_kernel<<<dim3(IDIM / 64, HDIM / 64, NEXP), 256, 0, stream>>>(w_gate, R1a, HDIM, IDIM);
    transpose_cvt_kernel<<<dim3(IDIM / 64, HDIM / 64, NEXP), 256, 0, stream>>>(w_up,   R1b, HDIM, IDIM);
    gateup_bf_kernel<true><<<dim3(IDIM / 128, NEXP * 16), 256, 0, stream>>>(
        Xb, R1a, R1b, hb, list, offs, cnt, IDIM);
    // expert down
    transpose_cvt_kernel<<<dim3(HDIM / 64, IDIM / 64, NEXP), 256, 0, stream>>>(w_down, R1a, IDIM, HDIM);
    down_bf_kernel<true><<<dim3(HDIM / 128, NEXP * 16), 256, 0, stream>>>(
        hb, R1a, out, list, wl, offs, cnt, IDIM);
  } else {
    // ---- legacy path (round-2, f32 weights on the fly) ----
    unsigned short* sh_buf = (unsigned short*)ws;
    unsigned short* h_buf  = (unsigned short*)(ws + 23068672);
    char* meta = ws + 34963456;
    int*   cnt   = (int*)(meta);
    int*   cur   = (int*)(meta + 256);
    int*   offs  = (int*)(meta + 512);
    int*   list  = (int*)(meta + 768);
    float* wl    = (float*)(meta + 768 + 17152);
    int*   tok_e = (int*)(meta + 768 + 2 * 17152);
    float* tok_w = (float*)(meta + 768 + 2 * 17152 + 16384);
    float* sg    = (float*)(meta + 768 + 2 * 17152 + 32768);

    hipMemsetAsync(meta, 0, 768 + 2 * 17152, stream);
    router_kernel<<<TOK, 256, 0, stream>>>(x, gate_w, sgw, cnt, tok_e, tok_w, sg);
    scan_kernel<<<1, 64, 0, stream>>>(cnt, offs);
    build_kernel<<<8, 256, 0, stream>>>(tok_e, tok_w, offs, cur, list, wl);
    gateup_kernel<false><<<dim3(ISDIM / 128, TOK / 128), 256, 0, stream>>>(
        x, sw_gate, sw_up, sh_buf, nullptr, nullptr, nullptr, ISDIM);
    down_kernel<false><<<dim3(HDIM / 128, TOK / 128), 256, 0, stream>>>(
        sh_buf, sw_down, out, nullptr, sg, nullptr, nullptr, ISDIM);
    gateup_kernel<true><<<dim3(IDIM / 128, NEXP * 16), 256, 0, stream>>>(
        x, w_gate, w_up, h_buf, list, offs, cnt, IDIM);
    down_kernel<true><<<dim3(HDIM / 128, NEXP * 16), 256, 0, stream>>>(
        h_buf, w_down, out, list, wl, offs, cnt, IDIM);
  }
}